// Round 1
// baseline (2609.740 us; speedup 1.0000x reference)
//
#include <hip/hip_runtime.h>

#define N_ATOMS 60000
#define FPD 120
#define HD 512
#define EE 3
#define BB 600
#define NNZ_C 5000000
#define NFORCE (3 * N_ATOMS)
#define TB 16
#define NTILES ((N_ATOMS + TB - 1) / TB)

// ---------------- build per-element atom lists ----------------
__global__ void build_lists(const int* __restrict__ z, int* __restrict__ counts,
                            int* __restrict__ lists) {
    int i = blockIdx.x * blockDim.x + threadIdx.x;
    if (i >= N_ATOMS) return;
    int zi = z[i];
    int e = (zi == 1) ? 0 : ((zi == 8) ? 1 : 2);
    int pos = atomicAdd(&counts[e], 1);
    lists[e * N_ATOMS + pos] = i;
}

// ---------------- transpose weights for coalesced backward ----------------
// W1: [E][FPD][HD] -> W1T: [E][HD][FPD]
__global__ void transpose_W1(const float* __restrict__ W1, float* __restrict__ W1T) {
    int idx = blockIdx.x * blockDim.x + threadIdx.x;
    if (idx >= EE * HD * FPD) return;
    int f = idx % FPD;
    int rest = idx / FPD;
    int i = rest % HD;
    int e = rest / HD;
    W1T[idx] = W1[(e * FPD + f) * HD + i];
}
// W2: [E][HD][HD] -> W2T: [E][HD][HD] (swap last two dims)
__global__ void transpose_W2(const float* __restrict__ W2, float* __restrict__ W2T) {
    int idx = blockIdx.x * blockDim.x + threadIdx.x;
    if (idx >= EE * HD * HD) return;
    int i2 = idx % HD;
    int rest = idx / HD;
    int j = rest % HD;
    int e = rest / HD;
    W2T[idx] = W2[(e * HD + i2) * HD + j];
}

// ---------------- fused MLP forward+backward, one 16-atom tile per block -------
// LDS layout: transposed [k][atom] so inner-product reads are lane-broadcast.
__global__ __launch_bounds__(256) void mlp_fused(
    const float* __restrict__ fps, const int* __restrict__ image_idx,
    const float* __restrict__ W1, const float* __restrict__ b1,
    const float* __restrict__ W2, const float* __restrict__ b2,
    const float* __restrict__ W3, const float* __restrict__ b3,
    const float* __restrict__ W1T, const float* __restrict__ W2T,
    const int* __restrict__ counts, const int* __restrict__ lists,
    float* __restrict__ energy_out, float* __restrict__ g) {
    __shared__ float bufA[HD * TB];  // h1 then dh1, [i][a]
    __shared__ float bufB[HD * TB];  // fingerprint tile [f][a], then h2/dh2 [j][a]

    const int e = blockIdx.x % EE;
    const int tile = blockIdx.x / EE;
    const int cnt = counts[e];
    const int base = tile * TB;
    if (base >= cnt) return;
    const int nA = min(TB, cnt - base);
    const int* lst = lists + e * N_ATOMS + base;
    const float* W1e = W1 + e * FPD * HD;
    const float* W2e = W2 + e * HD * HD;
    const float* W3e = W3 + e * HD;
    const float* b1e = b1 + e * HD;
    const float* b2e = b2 + e * HD;
    const float b3e = b3[e];
    const float* W1Te = W1T + e * HD * FPD;
    const float* W2Te = W2T + e * HD * HD;
    const int t = threadIdx.x;

    // load fingerprint tile, transposed [f][a]; pad columns with 0
    for (int idx = t; idx < FPD * TB; idx += 256) {
        int a = idx % TB;
        int f = idx / TB;
        float v = 0.f;
        if (a < nA) v = fps[(long)lst[a] * FPD + f];
        bufB[idx] = v;
    }
    __syncthreads();

    // ---- stage 1: h1 = tanh(fp @ W1 + b1) -> bufA[j][a] ----
    {
        const int j0 = t * 2;
        float acc0[TB], acc1[TB];
#pragma unroll
        for (int a = 0; a < TB; a++) { acc0[a] = 0.f; acc1[a] = 0.f; }
        for (int f = 0; f < FPD; f++) {
            float w0 = W1e[f * HD + j0];
            float w1 = W1e[f * HD + j0 + 1];
#pragma unroll
            for (int a = 0; a < TB; a++) {
                float x = bufB[f * TB + a];
                acc0[a] += x * w0;
                acc1[a] += x * w1;
            }
        }
        float bb0 = b1e[j0], bb1 = b1e[j0 + 1];
#pragma unroll
        for (int a = 0; a < TB; a++) {
            bufA[j0 * TB + a] = tanhf(acc0[a] + bb0);
            bufA[(j0 + 1) * TB + a] = tanhf(acc1[a] + bb1);
        }
    }
    __syncthreads();

    // ---- stage 2: h2 = tanh(h1 @ W2 + b2) -> bufB[j][a] (fp tile now dead) ----
    {
        const int j0 = t * 2;
        float acc0[TB], acc1[TB];
#pragma unroll
        for (int a = 0; a < TB; a++) { acc0[a] = 0.f; acc1[a] = 0.f; }
        for (int i = 0; i < HD; i++) {
            float w0 = W2e[i * HD + j0];
            float w1 = W2e[i * HD + j0 + 1];
#pragma unroll
            for (int a = 0; a < TB; a++) {
                float x = bufA[i * TB + a];
                acc0[a] += x * w0;
                acc1[a] += x * w1;
            }
        }
        float bb0 = b2e[j0], bb1 = b2e[j0 + 1];
#pragma unroll
        for (int a = 0; a < TB; a++) {
            bufB[j0 * TB + a] = tanhf(acc0[a] + bb0);
            bufB[(j0 + 1) * TB + a] = tanhf(acc1[a] + bb1);
        }
    }
    __syncthreads();

    // ---- stage 3: out[a] = sum_j h2[j][a]*W3[j] + b3 -> atomicAdd energy ----
    {
        const int a = t & 15;
        const int chunk = t >> 4;  // 16 chunks of 32 j's
        float part = 0.f;
        const int jb = chunk * 32;
        for (int j = jb; j < jb + 32; j++) part += bufB[j * TB + a] * W3e[j];
        part += __shfl_down(part, 32, 64);
        part += __shfl_down(part, 16, 64);
        if ((t & 63) < 16 && a < nA) {
            float val = part + ((t >> 6) == 0 ? b3e : 0.f);
            int img = image_idx[lst[a]];
            atomicAdd(&energy_out[img], val);
        }
    }
    __syncthreads();

    // ---- stage 4: dh2[j][a] = W3[j]*(1-h2^2), in place in bufB ----
    for (int idx = t; idx < HD * TB; idx += 256) {
        int j = idx / TB;
        float h2 = bufB[idx];
        bufB[idx] = W3e[j] * (1.f - h2 * h2);
    }
    __syncthreads();

    // ---- stage 5: dh1[i][a] = (sum_j W2[i][j]*dh2[j][a]) * (1-h1^2), in bufA ----
    {
        const int i0 = t * 2;
        float acc0[TB], acc1[TB];
#pragma unroll
        for (int a = 0; a < TB; a++) { acc0[a] = 0.f; acc1[a] = 0.f; }
        for (int j = 0; j < HD; j++) {
            float w0 = W2Te[j * HD + i0];      // = W2[i0][j]
            float w1 = W2Te[j * HD + i0 + 1];  // = W2[i0+1][j]
#pragma unroll
            for (int a = 0; a < TB; a++) {
                float x = bufB[j * TB + a];
                acc0[a] += x * w0;
                acc1[a] += x * w1;
            }
        }
#pragma unroll
        for (int a = 0; a < TB; a++) {
            float h10 = bufA[i0 * TB + a];
            float h11 = bufA[(i0 + 1) * TB + a];
            bufA[i0 * TB + a] = acc0[a] * (1.f - h10 * h10);
            bufA[(i0 + 1) * TB + a] = acc1[a] * (1.f - h11 * h11);
        }
    }
    __syncthreads();

    // ---- stage 7: g[atom][f] = sum_i W1[f][i]*dh1[i][a] ----
    for (int idx = t; idx < TB * FPD; idx += 256) {
        int a = idx / FPD;
        int f = idx % FPD;
        if (a < nA) {
            float acc = 0.f;
#pragma unroll 8
            for (int i = 0; i < HD; i++) acc += bufA[i * TB + a] * W1Te[i * FPD + f];
            g[(long)lst[a] * FPD + f] = acc;
        }
    }
}

// ---------------- sparse force scatter ----------------
__global__ void scatter_forces(const int* __restrict__ rows, const int* __restrict__ cols,
                               const float* __restrict__ vals, const float* __restrict__ g,
                               float* __restrict__ forces) {
    int k = blockIdx.x * blockDim.x + threadIdx.x;
    if (k >= NNZ_C) return;
    float v = -vals[k] * g[rows[k]];
    atomicAdd(&forces[cols[k]], v);
}

extern "C" void kernel_launch(void* const* d_in, const int* in_sizes, int n_in,
                              void* d_out, int out_size, void* d_ws, size_t ws_size,
                              hipStream_t stream) {
    const float* fps = (const float*)d_in[0];
    const int* z = (const int*)d_in[1];
    const int* img = (const int*)d_in[2];
    const float* W1 = (const float*)d_in[3];
    const float* b1 = (const float*)d_in[4];
    const float* W2 = (const float*)d_in[5];
    const float* b2 = (const float*)d_in[6];
    const float* W3 = (const float*)d_in[7];
    const float* b3 = (const float*)d_in[8];
    const int* rows = (const int*)d_in[9];
    const int* cols = (const int*)d_in[10];
    const float* vals = (const float*)d_in[11];

    float* out = (float*)d_out;
    float* energy = out;
    float* forces = out + BB;

    char* ws = (char*)d_ws;
    int* counts = (int*)ws;                        // 12 B (zeroed below)
    int* lists = (int*)(ws + 256);                 // 720000 B
    float* W1T = (float*)(ws + 720384);            // 737280 B
    float* W2T = (float*)(ws + 1457664);           // 3145728 B
    float* g = (float*)(ws + 4603392);             // 28.8 MB
    (void)in_sizes; (void)n_in; (void)out_size; (void)ws_size;

    hipMemsetAsync(d_out, 0, (size_t)(BB + NFORCE) * sizeof(float), stream);
    hipMemsetAsync(d_ws, 0, 256, stream);

    build_lists<<<(N_ATOMS + 255) / 256, 256, 0, stream>>>(z, counts, lists);
    transpose_W1<<<(EE * HD * FPD + 255) / 256, 256, 0, stream>>>(W1, W1T);
    transpose_W2<<<(EE * HD * HD + 255) / 256, 256, 0, stream>>>(W2, W2T);
    mlp_fused<<<EE * NTILES, 256, 0, stream>>>(fps, img, W1, b1, W2, b2, W3, b3,
                                               W1T, W2T, counts, lists, energy, g);
    scatter_forces<<<(NNZ_C + 255) / 256, 256, 0, stream>>>(rows, cols, vals, g, forces);
}

// Round 2
// 1573.998 us; speedup vs baseline: 1.6580x; 1.6580x over previous
//
#include <hip/hip_runtime.h>

#define N_ATOMS 60000
#define FPD 120
#define HD 512
#define EE 3
#define BB 600
#define NNZ_C 5000000
#define NFORCE (3 * N_ATOMS)

typedef unsigned short ushort_t;
typedef unsigned int uint_t;
typedef __attribute__((ext_vector_type(8))) __bf16 bf16x8;
typedef __attribute__((ext_vector_type(4))) float f32x4;

union BF8 { f32x4 f; bf16x8 h; };

__device__ __forceinline__ ushort_t f2bf(float x) {
    uint_t u = __builtin_bit_cast(uint_t, x);
    u = (u + 0x7FFFu + ((u >> 16) & 1u)) >> 16;
    return (ushort_t)u;
}
__device__ __forceinline__ float bf2f(ushort_t s) {
    uint_t u = ((uint_t)s) << 16;
    return __builtin_bit_cast(float, u);
}
__device__ __forceinline__ float fast_tanh(float x) {
    float e2 = __expf(2.f * x);            // v_exp_f32 path
    return fmaf(-2.f, __frcp_rn(e2 + 1.f), 1.f);
}

// ---------------- build per-element atom lists ----------------
__global__ void build_lists(const int* __restrict__ z, int* __restrict__ counts,
                            int* __restrict__ lists) {
    int i = blockIdx.x * blockDim.x + threadIdx.x;
    if (i >= N_ATOMS) return;
    int zi = z[i];
    int e = (zi == 1) ? 0 : ((zi == 8) ? 1 : 2);
    int pos = atomicAdd(&counts[e], 1);
    lists[e * N_ATOMS + pos] = i;
}

// ---------------- pack weights into MFMA B-fragment order (bf16) ----------------
// B-frag: lane L holds B[k = ks*32 + (L>>4)*8 + j][n = ct*16 + (L&15)], j=0..7.
// Packed layout: [e][ct][ks][L*8+j], 16B-coalesced per-lane loads.

// W2p[e][32][16][512] = W2[k][n];  W2Tp same dims = W2[n][k]
__global__ void pack_W2(const float* __restrict__ W2, ushort_t* __restrict__ W2p,
                        ushort_t* __restrict__ W2Tp) {
    int p = blockIdx.x * 256 + threadIdx.x;
    if (p >= EE * 32 * 16 * 512) return;
    int j = p & 7, L = (p >> 3) & 63, ks = (p >> 9) & 15, ct = (p >> 13) & 31, e = p >> 18;
    int k = ks * 32 + ((L >> 4) << 3) + j;
    int n = (ct << 4) + (L & 15);
    W2p[p]  = f2bf(W2[((e << 9) + k) * 512 + n]);
    W2Tp[p] = f2bf(W2[((e << 9) + n) * 512 + k]);
}
// W1p[e][32][4][512] = W1[k][n] (K=120 zero-padded to 128)
__global__ void pack_W1(const float* __restrict__ W1, ushort_t* __restrict__ W1p) {
    int p = blockIdx.x * 256 + threadIdx.x;
    if (p >= EE * 32 * 4 * 512) return;
    int j = p & 7, L = (p >> 3) & 63, ks = (p >> 9) & 3, ct = (p >> 11) & 31, e = p >> 16;
    int k = ks * 32 + ((L >> 4) << 3) + j;
    int n = (ct << 4) + (L & 15);
    W1p[p] = (k < FPD) ? f2bf(W1[(e * FPD + k) * 512 + n]) : (ushort_t)0;
}
// W1Tp[e][8][16][512] = W1[n][k] (N=120 zero-padded to 128)
__global__ void pack_W1T(const float* __restrict__ W1, ushort_t* __restrict__ W1Tp) {
    int p = blockIdx.x * 256 + threadIdx.x;
    if (p >= EE * 8 * 16 * 512) return;
    int j = p & 7, L = (p >> 3) & 63, ks = (p >> 9) & 15, ct = (p >> 13) & 7, e = p >> 16;
    int k = ks * 32 + ((L >> 4) << 3) + j;
    int n = (ct << 4) + (L & 15);
    W1Tp[p] = (n < FPD) ? f2bf(W1[(e * FPD + n) * 512 + k]) : (ushort_t)0;
}

#define STR 520   // sH1/sD row stride in ushorts (512 + 8 pad -> conflict-free)
#define FSTR 136  // fp-tile row stride (128 + 8 pad)

// ---------------- fused fwd+bwd MLP, 32 atoms/block, MFMA ----------------
__global__ __launch_bounds__(256) void mlp_mfma(
    const float* __restrict__ fps, const int* __restrict__ image_idx,
    const float* __restrict__ b1, const float* __restrict__ b2,
    const float* __restrict__ W3, const float* __restrict__ b3,
    const ushort_t* __restrict__ W1p, const ushort_t* __restrict__ W2p,
    const ushort_t* __restrict__ W2Tp, const ushort_t* __restrict__ W1Tp,
    const int* __restrict__ counts, const int* __restrict__ lists,
    float* __restrict__ energy, float* __restrict__ g) {
    __shared__ ushort_t sH1[32 * STR];  // h1, later dh1   (33280 B)
    __shared__ ushort_t sD[32 * STR];   // fp tile, later dh2 (33280 B)
    __shared__ float sW3[512];
    __shared__ float eAcc[32];
    __shared__ int sAtom[32];
    __shared__ int sImg[32];

    const int e = blockIdx.x % EE;
    const int tile = blockIdx.x / EE;
    const int cnt = counts[e];
    const int base = tile * 32;
    if (base >= cnt) return;
    const int nA = min(32, cnt - base);
    const int* lst = lists + e * N_ATOMS + base;

    const int t = threadIdx.x;
    const int w = t >> 6, lane = t & 63, quad = lane >> 4, lc = lane & 15;

    if (t < 32) {
        int a = (t < nA) ? lst[t] : -1;
        sAtom[t] = a;
        sImg[t] = (a >= 0) ? image_idx[a] : 0;
        eAcc[t] = 0.f;
    }
    for (int i = t; i < 512; i += 256) sW3[i] = W3[e * 512 + i];
    // fingerprint tile -> sD (bf16, [a][f], stride FSTR)
    for (int i = t; i < 32 * 128; i += 256) {
        int a = i >> 7, f = i & 127;
        float v = 0.f;
        if (f < FPD && a < nA) v = fps[(long long)lst[a] * FPD + f];
        sD[a * FSTR + f] = f2bf(v);
    }
    __syncthreads();

    // per-lane bias columns for this wave's 8 col-tiles
    float b1c[8], b2c[8];
#pragma unroll
    for (int ct = 0; ct < 8; ct++) {
        int col = w * 128 + ct * 16 + lc;
        b1c[ct] = b1[e * 512 + col];
        b2c[ct] = b2[e * 512 + col];
    }

    f32x4 acc[2][8];

    // ---- stage 1: h1 = tanh(fp @ W1 + b1), K=128(pad), N=512 ----
#pragma unroll
    for (int rt = 0; rt < 2; rt++)
#pragma unroll
        for (int ct = 0; ct < 8; ct++) acc[rt][ct] = (f32x4)0.f;
    for (int ks = 0; ks < 4; ks++) {
        bf16x8 a0 = *(const bf16x8*)((const char*)sD + lc * (FSTR * 2) + ks * 64 + quad * 16);
        bf16x8 a1 = *(const bf16x8*)((const char*)sD + (16 + lc) * (FSTR * 2) + ks * 64 + quad * 16);
#pragma unroll
        for (int ct = 0; ct < 8; ct++) {
            BF8 b;
            b.f = *(const f32x4*)(W1p + (((size_t)(e * 32 + w * 8 + ct) * 4 + ks) * 512) + lane * 8);
            acc[0][ct] = __builtin_amdgcn_mfma_f32_16x16x32_bf16(a0, b.h, acc[0][ct], 0, 0, 0);
            acc[1][ct] = __builtin_amdgcn_mfma_f32_16x16x32_bf16(a1, b.h, acc[1][ct], 0, 0, 0);
        }
    }
#pragma unroll
    for (int ct = 0; ct < 8; ct++) {
        int col = w * 128 + ct * 16 + lc;
#pragma unroll
        for (int rt = 0; rt < 2; rt++)
#pragma unroll
            for (int r = 0; r < 4; r++) {
                int row = rt * 16 + quad * 4 + r;
                sH1[row * STR + col] = f2bf(fast_tanh(acc[rt][ct][r] + b1c[ct]));
            }
    }
    __syncthreads();

    // ---- stage 2: h2 = tanh(h1 @ W2 + b2); dh2 = W3*(1-h2^2); energy partials ----
#pragma unroll
    for (int rt = 0; rt < 2; rt++)
#pragma unroll
        for (int ct = 0; ct < 8; ct++) acc[rt][ct] = (f32x4)0.f;
    for (int ks = 0; ks < 16; ks++) {
        bf16x8 a0 = *(const bf16x8*)((const char*)sH1 + lc * (STR * 2) + ks * 64 + quad * 16);
        bf16x8 a1 = *(const bf16x8*)((const char*)sH1 + (16 + lc) * (STR * 2) + ks * 64 + quad * 16);
#pragma unroll
        for (int ct = 0; ct < 8; ct++) {
            BF8 b;
            b.f = *(const f32x4*)(W2p + (((size_t)(e * 32 + w * 8 + ct) * 16 + ks) * 512) + lane * 8);
            acc[0][ct] = __builtin_amdgcn_mfma_f32_16x16x32_bf16(a0, b.h, acc[0][ct], 0, 0, 0);
            acc[1][ct] = __builtin_amdgcn_mfma_f32_16x16x32_bf16(a1, b.h, acc[1][ct], 0, 0, 0);
        }
    }
    {
        float ep[2][4];
#pragma unroll
        for (int rt = 0; rt < 2; rt++)
#pragma unroll
            for (int r = 0; r < 4; r++) ep[rt][r] = 0.f;
#pragma unroll
        for (int ct = 0; ct < 8; ct++) {
            int col = w * 128 + ct * 16 + lc;
            float w3c = sW3[col];
#pragma unroll
            for (int rt = 0; rt < 2; rt++)
#pragma unroll
                for (int r = 0; r < 4; r++) {
                    int row = rt * 16 + quad * 4 + r;
                    float h2 = fast_tanh(acc[rt][ct][r] + b2c[ct]);
                    ep[rt][r] += h2 * w3c;
                    sD[row * STR + col] = f2bf(w3c * (1.f - h2 * h2));
                }
        }
#pragma unroll
        for (int rt = 0; rt < 2; rt++)
#pragma unroll
            for (int r = 0; r < 4; r++) {
                float p = ep[rt][r];
                p += __shfl_xor(p, 1);
                p += __shfl_xor(p, 2);
                p += __shfl_xor(p, 4);
                p += __shfl_xor(p, 8);
                if (lc == 0) atomicAdd(&eAcc[rt * 16 + quad * 4 + r], p);
            }
    }
    __syncthreads();

    // energy finalize (one thread per atom row)
    if (t < nA) atomicAdd(&energy[sImg[t]], eAcc[t] + b3[e]);

    // ---- stage 5: dh1 = (dh2 @ W2^T) * (1-h1^2) ----
#pragma unroll
    for (int rt = 0; rt < 2; rt++)
#pragma unroll
        for (int ct = 0; ct < 8; ct++) acc[rt][ct] = (f32x4)0.f;
    for (int ks = 0; ks < 16; ks++) {
        bf16x8 a0 = *(const bf16x8*)((const char*)sD + lc * (STR * 2) + ks * 64 + quad * 16);
        bf16x8 a1 = *(const bf16x8*)((const char*)sD + (16 + lc) * (STR * 2) + ks * 64 + quad * 16);
#pragma unroll
        for (int ct = 0; ct < 8; ct++) {
            BF8 b;
            b.f = *(const f32x4*)(W2Tp + (((size_t)(e * 32 + w * 8 + ct) * 16 + ks) * 512) + lane * 8);
            acc[0][ct] = __builtin_amdgcn_mfma_f32_16x16x32_bf16(a0, b.h, acc[0][ct], 0, 0, 0);
            acc[1][ct] = __builtin_amdgcn_mfma_f32_16x16x32_bf16(a1, b.h, acc[1][ct], 0, 0, 0);
        }
    }
#pragma unroll
    for (int ct = 0; ct < 8; ct++) {
        int col = w * 128 + ct * 16 + lc;
#pragma unroll
        for (int rt = 0; rt < 2; rt++)
#pragma unroll
            for (int r = 0; r < 4; r++) {
                int row = rt * 16 + quad * 4 + r;
                float h1v = bf2f(sH1[row * STR + col]);
                acc[rt][ct][r] *= (1.f - h1v * h1v);
            }
    }
    __syncthreads();  // all h1 mask reads done
#pragma unroll
    for (int ct = 0; ct < 8; ct++) {
        int col = w * 128 + ct * 16 + lc;
#pragma unroll
        for (int rt = 0; rt < 2; rt++)
#pragma unroll
            for (int r = 0; r < 4; r++) {
                int row = rt * 16 + quad * 4 + r;
                sH1[row * STR + col] = f2bf(acc[rt][ct][r]);  // sH1 now holds dh1
            }
    }
    __syncthreads();

    // ---- stage 7: g = dh1 @ W1^T, N=128(pad->120) ----
    f32x4 acc7[2][2];
#pragma unroll
    for (int rt = 0; rt < 2; rt++)
#pragma unroll
        for (int c = 0; c < 2; c++) acc7[rt][c] = (f32x4)0.f;
    for (int ks = 0; ks < 16; ks++) {
        bf16x8 a0 = *(const bf16x8*)((const char*)sH1 + lc * (STR * 2) + ks * 64 + quad * 16);
        bf16x8 a1 = *(const bf16x8*)((const char*)sH1 + (16 + lc) * (STR * 2) + ks * 64 + quad * 16);
#pragma unroll
        for (int c = 0; c < 2; c++) {
            BF8 b;
            b.f = *(const f32x4*)(W1Tp + (((size_t)(e * 8 + w * 2 + c) * 16 + ks) * 512) + lane * 8);
            acc7[0][c] = __builtin_amdgcn_mfma_f32_16x16x32_bf16(a0, b.h, acc7[0][c], 0, 0, 0);
            acc7[1][c] = __builtin_amdgcn_mfma_f32_16x16x32_bf16(a1, b.h, acc7[1][c], 0, 0, 0);
        }
    }
#pragma unroll
    for (int c = 0; c < 2; c++) {
        int col = (w * 2 + c) * 16 + lc;
#pragma unroll
        for (int rt = 0; rt < 2; rt++)
#pragma unroll
            for (int r = 0; r < 4; r++) {
                int row = rt * 16 + quad * 4 + r;
                if (col < FPD && row < nA)
                    g[(long long)sAtom[row] * FPD + col] = acc7[rt][c][r];
            }
    }
}

// ---------------- sparse force scatter ----------------
__global__ void scatter_forces(const int* __restrict__ rows, const int* __restrict__ cols,
                               const float* __restrict__ vals, const float* __restrict__ g,
                               float* __restrict__ forces) {
    int k = blockIdx.x * blockDim.x + threadIdx.x;
    if (k >= NNZ_C) return;
    float v = -vals[k] * g[rows[k]];
    atomicAdd(&forces[cols[k]], v);
}

extern "C" void kernel_launch(void* const* d_in, const int* in_sizes, int n_in,
                              void* d_out, int out_size, void* d_ws, size_t ws_size,
                              hipStream_t stream) {
    const float* fps = (const float*)d_in[0];
    const int* z = (const int*)d_in[1];
    const int* img = (const int*)d_in[2];
    const float* W1 = (const float*)d_in[3];
    const float* b1 = (const float*)d_in[4];
    const float* W2 = (const float*)d_in[5];
    const float* b2 = (const float*)d_in[6];
    const float* W3 = (const float*)d_in[7];
    const float* b3 = (const float*)d_in[8];
    const int* rows = (const int*)d_in[9];
    const int* cols = (const int*)d_in[10];
    const float* vals = (const float*)d_in[11];

    float* out = (float*)d_out;
    float* energy = out;
    float* forces = out + BB;

    char* ws = (char*)d_ws;
    int* counts = (int*)ws;                           // 12 B
    int* lists = (int*)(ws + 256);                    // 720000 B
    ushort_t* W1p = (ushort_t*)(ws + 720384);         // 393216 B
    ushort_t* W2p = (ushort_t*)(ws + 1113600);        // 1572864 B
    ushort_t* W2Tp = (ushort_t*)(ws + 2686464);       // 1572864 B
    ushort_t* W1Tp = (ushort_t*)(ws + 4259328);       // 393216 B
    float* g = (float*)(ws + 4652544);                // 28800000 B
    (void)in_sizes; (void)n_in; (void)out_size; (void)ws_size;

    hipMemsetAsync(d_out, 0, (size_t)(BB + NFORCE) * sizeof(float), stream);
    hipMemsetAsync(d_ws, 0, 256, stream);

    build_lists<<<(N_ATOMS + 255) / 256, 256, 0, stream>>>(z, counts, lists);
    pack_W2<<<(EE * 32 * 16 * 512 + 255) / 256, 256, 0, stream>>>(W2, W2p, W2Tp);
    pack_W1<<<(EE * 32 * 4 * 512 + 255) / 256, 256, 0, stream>>>(W1, W1p);
    pack_W1T<<<(EE * 8 * 16 * 512 + 255) / 256, 256, 0, stream>>>(W1, W1Tp);

    int tiles = (N_ATOMS + 31) / 32;
    mlp_mfma<<<EE * tiles, 256, 0, stream>>>(fps, img, b1, b2, W3, b3,
                                             W1p, W2p, W2Tp, W1Tp,
                                             counts, lists, energy, g);
    scatter_forces<<<(NNZ_C + 255) / 256, 256, 0, stream>>>(rows, cols, vals, g, forces);
}

// Round 3
// 1047.279 us; speedup vs baseline: 2.4919x; 1.5029x over previous
//
#include <hip/hip_runtime.h>

#define N_ATOMS 60000
#define FPD 120
#define HD 512
#define EE 3
#define BB 600
#define NNZ_C 5000000
#define NFORCE (3 * N_ATOMS)

typedef unsigned short ushort_t;
typedef unsigned int uint_t;
typedef __attribute__((ext_vector_type(8))) __bf16 bf16x8;
typedef __attribute__((ext_vector_type(4))) float f32x4;

union BF8 { f32x4 f; bf16x8 h; };

__device__ __forceinline__ ushort_t f2bf(float x) {
    uint_t u = __builtin_bit_cast(uint_t, x);
    u = (u + 0x7FFFu + ((u >> 16) & 1u)) >> 16;
    return (ushort_t)u;
}
__device__ __forceinline__ float bf2f(ushort_t s) {
    uint_t u = ((uint_t)s) << 16;
    return __builtin_bit_cast(float, u);
}
__device__ __forceinline__ float fast_tanh(float x) {
    float e2 = __expf(2.f * x);
    return fmaf(-2.f, __frcp_rn(e2 + 1.f), 1.f);
}

// ---------------- build per-element atom lists ----------------
__global__ void build_lists(const int* __restrict__ z, int* __restrict__ counts,
                            int* __restrict__ lists) {
    int i = blockIdx.x * blockDim.x + threadIdx.x;
    if (i >= N_ATOMS) return;
    int zi = z[i];
    int e = (zi == 1) ? 0 : ((zi == 8) ? 1 : 2);
    int pos = atomicAdd(&counts[e], 1);
    lists[e * N_ATOMS + pos] = i;
}

// ---------------- pack weights into MFMA B-fragment order (bf16) ----------------
// Lane L of B-frag holds B[k = ks*32 + (L>>4)*8 + j][n = ct*16 + (L&15)], j=0..7.
// Layout: ks OUTER, ct inner -> a wave's 8 per-iteration loads span 8KB
// contiguous (spreads over all L2 channels; old ct-outer layout had 16KB
// stride == channel-camping, 4x L2 BW loss).

// W2p[e][ks:16][ct:32][512] = W2[k][n];  W2Tp same dims = W2[n][k]
__global__ void pack_W2(const float* __restrict__ W2, ushort_t* __restrict__ W2p,
                        ushort_t* __restrict__ W2Tp) {
    int p = blockIdx.x * 256 + threadIdx.x;
    if (p >= EE * 16 * 32 * 512) return;
    int j = p & 7, L = (p >> 3) & 63, ct = (p >> 9) & 31, ks = (p >> 14) & 15, e = p >> 18;
    int k = ks * 32 + ((L >> 4) << 3) + j;
    int n = (ct << 4) + (L & 15);
    W2p[p]  = f2bf(W2[((e << 9) + k) * 512 + n]);
    W2Tp[p] = f2bf(W2[((e << 9) + n) * 512 + k]);
}
// W1p[e][ks:4][ct:32][512] = W1[k][n], k>=120 -> 0
__global__ void pack_W1(const float* __restrict__ W1, ushort_t* __restrict__ W1p) {
    int p = blockIdx.x * 256 + threadIdx.x;
    if (p >= EE * 4 * 32 * 512) return;
    int j = p & 7, L = (p >> 3) & 63, ct = (p >> 9) & 31, ks = (p >> 14) & 3, e = p >> 16;
    int k = ks * 32 + ((L >> 4) << 3) + j;
    int n = (ct << 4) + (L & 15);
    W1p[p] = (k < FPD) ? f2bf(W1[(e * FPD + k) * 512 + n]) : (ushort_t)0;
}
// W1Tp[e][ks:16][ct:8][512] = W1[n][k], n>=120 -> 0
__global__ void pack_W1T(const float* __restrict__ W1, ushort_t* __restrict__ W1Tp) {
    int p = blockIdx.x * 256 + threadIdx.x;
    if (p >= EE * 16 * 8 * 512) return;
    int j = p & 7, L = (p >> 3) & 63, ct = (p >> 9) & 7, ks = (p >> 12) & 15, e = p >> 16;
    int k = ks * 32 + ((L >> 4) << 3) + j;
    int n = (ct << 4) + (L & 15);
    W1Tp[p] = (n < FPD) ? f2bf(W1[(e * FPD + n) * 512 + k]) : (ushort_t)0;
}

#define STR 520   // sH1/sD row stride in ushorts (512 + 8 pad)
#define FSTR 136  // fp-tile row stride (128 + 8 pad)

// ---------------- fused fwd+bwd MLP, 32 atoms/block, MFMA ----------------
__global__ __launch_bounds__(256) void mlp_mfma(
    const float* __restrict__ fps, const int* __restrict__ image_idx,
    const float* __restrict__ b1, const float* __restrict__ b2,
    const float* __restrict__ W3, const float* __restrict__ b3,
    const ushort_t* __restrict__ W1p, const ushort_t* __restrict__ W2p,
    const ushort_t* __restrict__ W2Tp, const ushort_t* __restrict__ W1Tp,
    const int* __restrict__ counts, const int* __restrict__ lists,
    float* __restrict__ energy, ushort_t* __restrict__ g) {
    __shared__ ushort_t sH1[32 * STR];  // h1, later dh1
    __shared__ ushort_t sD[32 * STR];   // fp tile, later dh2
    __shared__ float sW3[512];
    __shared__ float eAcc[32];
    __shared__ int sAtom[32];
    __shared__ int sImg[32];

    const int e = blockIdx.x % EE;
    const int tile = blockIdx.x / EE;
    const int cnt = counts[e];
    const int base = tile * 32;
    if (base >= cnt) return;
    const int nA = min(32, cnt - base);
    const int* lst = lists + e * N_ATOMS + base;

    const int t = threadIdx.x;
    const int w = t >> 6, lane = t & 63, quad = lane >> 4, lc = lane & 15;

    if (t < 32) {
        int a = (t < nA) ? lst[t] : -1;
        sAtom[t] = a;
        sImg[t] = (a >= 0) ? image_idx[a] : 0;
        eAcc[t] = 0.f;
    }
    for (int i = t; i < 512; i += 256) sW3[i] = W3[e * 512 + i];
    for (int i = t; i < 32 * 128; i += 256) {
        int a = i >> 7, f = i & 127;
        float v = 0.f;
        if (f < FPD && a < nA) v = fps[(long long)lst[a] * FPD + f];
        sD[a * FSTR + f] = f2bf(v);
    }
    __syncthreads();

    float b1c[8], b2c[8];
#pragma unroll
    for (int ct = 0; ct < 8; ct++) {
        int col = w * 128 + ct * 16 + lc;
        b1c[ct] = b1[e * 512 + col];
        b2c[ct] = b2[e * 512 + col];
    }

    f32x4 acc[2][8];

    // ---- stage 1: h1 = tanh(fp @ W1 + b1) ----
#pragma unroll
    for (int rt = 0; rt < 2; rt++)
#pragma unroll
        for (int ct = 0; ct < 8; ct++) acc[rt][ct] = (f32x4)0.f;
#pragma unroll
    for (int ks = 0; ks < 4; ks++) {
        bf16x8 a0 = *(const bf16x8*)((const char*)sD + lc * (FSTR * 2) + ks * 64 + quad * 16);
        bf16x8 a1 = *(const bf16x8*)((const char*)sD + (16 + lc) * (FSTR * 2) + ks * 64 + quad * 16);
#pragma unroll
        for (int ct = 0; ct < 8; ct++) {
            BF8 b;
            b.f = *(const f32x4*)(W1p + ((size_t)((e * 4 + ks) * 32 + w * 8 + ct) * 512) + lane * 8);
            acc[0][ct] = __builtin_amdgcn_mfma_f32_16x16x32_bf16(a0, b.h, acc[0][ct], 0, 0, 0);
            acc[1][ct] = __builtin_amdgcn_mfma_f32_16x16x32_bf16(a1, b.h, acc[1][ct], 0, 0, 0);
        }
    }
#pragma unroll
    for (int ct = 0; ct < 8; ct++) {
        int col = w * 128 + ct * 16 + lc;
#pragma unroll
        for (int rt = 0; rt < 2; rt++)
#pragma unroll
            for (int r = 0; r < 4; r++) {
                int row = rt * 16 + quad * 4 + r;
                sH1[row * STR + col] = f2bf(fast_tanh(acc[rt][ct][r] + b1c[ct]));
            }
    }
    __syncthreads();

    // ---- stage 2: h2 = tanh(h1 @ W2 + b2); dh2 = W3*(1-h2^2); energy ----
#pragma unroll
    for (int rt = 0; rt < 2; rt++)
#pragma unroll
        for (int ct = 0; ct < 8; ct++) acc[rt][ct] = (f32x4)0.f;
#pragma unroll 2
    for (int ks = 0; ks < 16; ks++) {
        bf16x8 a0 = *(const bf16x8*)((const char*)sH1 + lc * (STR * 2) + ks * 64 + quad * 16);
        bf16x8 a1 = *(const bf16x8*)((const char*)sH1 + (16 + lc) * (STR * 2) + ks * 64 + quad * 16);
#pragma unroll
        for (int ct = 0; ct < 8; ct++) {
            BF8 b;
            b.f = *(const f32x4*)(W2p + ((size_t)((e * 16 + ks) * 32 + w * 8 + ct) * 512) + lane * 8);
            acc[0][ct] = __builtin_amdgcn_mfma_f32_16x16x32_bf16(a0, b.h, acc[0][ct], 0, 0, 0);
            acc[1][ct] = __builtin_amdgcn_mfma_f32_16x16x32_bf16(a1, b.h, acc[1][ct], 0, 0, 0);
        }
    }
    {
        float ep[2][4];
#pragma unroll
        for (int rt = 0; rt < 2; rt++)
#pragma unroll
            for (int r = 0; r < 4; r++) ep[rt][r] = 0.f;
#pragma unroll
        for (int ct = 0; ct < 8; ct++) {
            int col = w * 128 + ct * 16 + lc;
            float w3c = sW3[col];
#pragma unroll
            for (int rt = 0; rt < 2; rt++)
#pragma unroll
                for (int r = 0; r < 4; r++) {
                    int row = rt * 16 + quad * 4 + r;
                    float h2 = fast_tanh(acc[rt][ct][r] + b2c[ct]);
                    ep[rt][r] += h2 * w3c;
                    sD[row * STR + col] = f2bf(w3c * (1.f - h2 * h2));
                }
        }
#pragma unroll
        for (int rt = 0; rt < 2; rt++)
#pragma unroll
            for (int r = 0; r < 4; r++) {
                float p = ep[rt][r];
                p += __shfl_xor(p, 1);
                p += __shfl_xor(p, 2);
                p += __shfl_xor(p, 4);
                p += __shfl_xor(p, 8);
                if (lc == 0) atomicAdd(&eAcc[rt * 16 + quad * 4 + r], p);
            }
    }
    __syncthreads();

    if (t < nA) atomicAdd(&energy[sImg[t]], eAcc[t] + b3[e]);

    // ---- stage 5: dh1 = (dh2 @ W2^T) * (1-h1^2) ----
#pragma unroll
    for (int rt = 0; rt < 2; rt++)
#pragma unroll
        for (int ct = 0; ct < 8; ct++) acc[rt][ct] = (f32x4)0.f;
#pragma unroll 2
    for (int ks = 0; ks < 16; ks++) {
        bf16x8 a0 = *(const bf16x8*)((const char*)sD + lc * (STR * 2) + ks * 64 + quad * 16);
        bf16x8 a1 = *(const bf16x8*)((const char*)sD + (16 + lc) * (STR * 2) + ks * 64 + quad * 16);
#pragma unroll
        for (int ct = 0; ct < 8; ct++) {
            BF8 b;
            b.f = *(const f32x4*)(W2Tp + ((size_t)((e * 16 + ks) * 32 + w * 8 + ct) * 512) + lane * 8);
            acc[0][ct] = __builtin_amdgcn_mfma_f32_16x16x32_bf16(a0, b.h, acc[0][ct], 0, 0, 0);
            acc[1][ct] = __builtin_amdgcn_mfma_f32_16x16x32_bf16(a1, b.h, acc[1][ct], 0, 0, 0);
        }
    }
#pragma unroll
    for (int ct = 0; ct < 8; ct++) {
        int col = w * 128 + ct * 16 + lc;
#pragma unroll
        for (int rt = 0; rt < 2; rt++)
#pragma unroll
            for (int r = 0; r < 4; r++) {
                int row = rt * 16 + quad * 4 + r;
                float h1v = bf2f(sH1[row * STR + col]);
                acc[rt][ct][r] *= (1.f - h1v * h1v);
            }
    }
    __syncthreads();
#pragma unroll
    for (int ct = 0; ct < 8; ct++) {
        int col = w * 128 + ct * 16 + lc;
#pragma unroll
        for (int rt = 0; rt < 2; rt++)
#pragma unroll
            for (int r = 0; r < 4; r++) {
                int row = rt * 16 + quad * 4 + r;
                sH1[row * STR + col] = f2bf(acc[rt][ct][r]);  // sH1 = dh1
            }
    }
    __syncthreads();

    // ---- stage 7: g = dh1 @ W1^T ----
    f32x4 acc7[2][2];
#pragma unroll
    for (int rt = 0; rt < 2; rt++)
#pragma unroll
        for (int c = 0; c < 2; c++) acc7[rt][c] = (f32x4)0.f;
#pragma unroll 2
    for (int ks = 0; ks < 16; ks++) {
        bf16x8 a0 = *(const bf16x8*)((const char*)sH1 + lc * (STR * 2) + ks * 64 + quad * 16);
        bf16x8 a1 = *(const bf16x8*)((const char*)sH1 + (16 + lc) * (STR * 2) + ks * 64 + quad * 16);
#pragma unroll
        for (int c = 0; c < 2; c++) {
            BF8 b;
            b.f = *(const f32x4*)(W1Tp + ((size_t)((e * 16 + ks) * 8 + w * 2 + c) * 512) + lane * 8);
            acc7[0][c] = __builtin_amdgcn_mfma_f32_16x16x32_bf16(a0, b.h, acc7[0][c], 0, 0, 0);
            acc7[1][c] = __builtin_amdgcn_mfma_f32_16x16x32_bf16(a1, b.h, acc7[1][c], 0, 0, 0);
        }
    }
#pragma unroll
    for (int c = 0; c < 2; c++) {
        int col = (w * 2 + c) * 16 + lc;
#pragma unroll
        for (int rt = 0; rt < 2; rt++)
#pragma unroll
            for (int r = 0; r < 4; r++) {
                int row = rt * 16 + quad * 4 + r;
                if (col < FPD && row < nA)
                    g[(long long)sAtom[row] * FPD + col] = f2bf(acc7[rt][c][r]);
            }
    }
}

// ---------------- sparse force scatter, XCD-privatized ----------------
__global__ void scatter_forces(const int* __restrict__ rows, const int* __restrict__ cols,
                               const float* __restrict__ vals, const ushort_t* __restrict__ g,
                               float* __restrict__ forcesP) {
    int k = blockIdx.x * blockDim.x + threadIdx.x;
    if (k >= NNZ_C) return;
    int slot = blockIdx.x & 7;  // ~XCD id under round-robin dispatch
    float v = -vals[k] * bf2f(g[rows[k]]);
    atomicAdd(&forcesP[slot * NFORCE + cols[k]], v);
}

__global__ void reduce_forces(const float* __restrict__ forcesP, float* __restrict__ forces) {
    int i = blockIdx.x * blockDim.x + threadIdx.x;
    if (i >= NFORCE) return;
    float s = 0.f;
#pragma unroll
    for (int x = 0; x < 8; x++) s += forcesP[x * NFORCE + i];
    forces[i] = s;
}

extern "C" void kernel_launch(void* const* d_in, const int* in_sizes, int n_in,
                              void* d_out, int out_size, void* d_ws, size_t ws_size,
                              hipStream_t stream) {
    const float* fps = (const float*)d_in[0];
    const int* z = (const int*)d_in[1];
    const int* img = (const int*)d_in[2];
    const float* W1 = (const float*)d_in[3];
    const float* b1 = (const float*)d_in[4];
    const float* W2 = (const float*)d_in[5];
    const float* b2 = (const float*)d_in[6];
    const float* W3 = (const float*)d_in[7];
    const float* b3 = (const float*)d_in[8];
    const int* rows = (const int*)d_in[9];
    const int* cols = (const int*)d_in[10];
    const float* vals = (const float*)d_in[11];

    float* out = (float*)d_out;
    float* energy = out;
    float* forces = out + BB;

    char* ws = (char*)d_ws;
    int* counts = (int*)ws;                           // 256 B
    int* lists = (int*)(ws + 256);                    // 720000 B
    ushort_t* W1p = (ushort_t*)(ws + 720384);         // 393216 B
    ushort_t* W2p = (ushort_t*)(ws + 1113600);        // 1572864 B
    ushort_t* W2Tp = (ushort_t*)(ws + 2686464);       // 1572864 B
    ushort_t* W1Tp = (ushort_t*)(ws + 4259328);       // 393216 B
    ushort_t* g = (ushort_t*)(ws + 4652544);          // 14400000 B
    float* forcesP = (float*)(ws + 19052544);         // 5760000 B -> 24812544
    (void)in_sizes; (void)n_in; (void)out_size; (void)ws_size;

    hipMemsetAsync(d_out, 0, (size_t)(BB + NFORCE) * sizeof(float), stream);
    hipMemsetAsync(counts, 0, 256, stream);
    hipMemsetAsync(forcesP, 0, (size_t)8 * NFORCE * sizeof(float), stream);

    build_lists<<<(N_ATOMS + 255) / 256, 256, 0, stream>>>(z, counts, lists);
    pack_W2<<<(EE * 16 * 32 * 512 + 255) / 256, 256, 0, stream>>>(W2, W2p, W2Tp);
    pack_W1<<<(EE * 4 * 32 * 512 + 255) / 256, 256, 0, stream>>>(W1, W1p);
    pack_W1T<<<(EE * 16 * 8 * 512 + 255) / 256, 256, 0, stream>>>(W1, W1Tp);

    int tiles = (N_ATOMS + 31) / 32;
    mlp_mfma<<<EE * tiles, 256, 0, stream>>>(fps, img, b1, b2, W3, b3,
                                             W1p, W2p, W2Tp, W1Tp,
                                             counts, lists, energy, g);
    scatter_forces<<<(NNZ_C + 255) / 256, 256, 0, stream>>>(rows, cols, vals, g, forcesP);
    reduce_forces<<<(NFORCE + 255) / 256, 256, 0, stream>>>(forcesP, forces);
}

// Round 4
// 671.313 us; speedup vs baseline: 3.8875x; 1.5600x over previous
//
#include <hip/hip_runtime.h>

#define N_ATOMS 60000
#define FPD 120
#define HD 512
#define EE 3
#define BB 600
#define NNZ_C 5000000
#define NFORCE (3 * N_ATOMS)

typedef unsigned short ushort_t;
typedef unsigned int uint_t;
typedef __attribute__((ext_vector_type(8))) __bf16 bf16x8;
typedef __attribute__((ext_vector_type(4))) float f32x4;

union BF8 { f32x4 f; bf16x8 h; };

__device__ __forceinline__ ushort_t f2bf(float x) {
    uint_t u = __builtin_bit_cast(uint_t, x);
    u = (u + 0x7FFFu + ((u >> 16) & 1u)) >> 16;
    return (ushort_t)u;
}
__device__ __forceinline__ float bf2f(ushort_t s) {
    uint_t u = ((uint_t)s) << 16;
    return __builtin_bit_cast(float, u);
}
__device__ __forceinline__ float fast_tanh(float x) {
    float e2 = __expf(2.f * x);
    return fmaf(-2.f, __frcp_rn(e2 + 1.f), 1.f);
}

// ---------------- build per-element atom lists (block-aggregated atomics) -----
// Old version: 60K device atomics on 3 addresses = 20K serialized/address = 380us.
// Now: LDS count + 3 global atomics per block (705 total).
__global__ __launch_bounds__(256) void build_lists(const int* __restrict__ z,
                                                   int* __restrict__ counts,
                                                   int* __restrict__ lists) {
    __shared__ int lc[3];
    __shared__ int lbase[3];
    const int t = threadIdx.x;
    if (t < 3) lc[t] = 0;
    __syncthreads();
    const int i = blockIdx.x * 256 + t;
    int e = 0, pos = 0;
    if (i < N_ATOMS) {
        int zi = z[i];
        e = (zi == 1) ? 0 : ((zi == 8) ? 1 : 2);
        pos = atomicAdd(&lc[e], 1);  // LDS atomic
    }
    __syncthreads();
    if (t < 3) lbase[t] = atomicAdd(&counts[t], lc[t]);  // 3 global atomics/block
    __syncthreads();
    if (i < N_ATOMS) lists[e * N_ATOMS + lbase[e] + pos] = i;
}

// ---------------- pack weights into MFMA B-fragment order (bf16) ----------------
// Lane L of B-frag holds B[k = ks*32 + (L>>4)*8 + j][n = ct*16 + (L&15)], j=0..7.
// ks OUTER, ct inner -> per-iteration wave loads span 8KB contiguous (all L2
// channels; ct-outer had 16KB stride = channel camping, 4x L2 BW loss).

__global__ void pack_W2(const float* __restrict__ W2, ushort_t* __restrict__ W2p,
                        ushort_t* __restrict__ W2Tp) {
    int p = blockIdx.x * 256 + threadIdx.x;
    if (p >= EE * 16 * 32 * 512) return;
    int j = p & 7, L = (p >> 3) & 63, ct = (p >> 9) & 31, ks = (p >> 14) & 15, e = p >> 18;
    int k = ks * 32 + ((L >> 4) << 3) + j;
    int n = (ct << 4) + (L & 15);
    W2p[p]  = f2bf(W2[((e << 9) + k) * 512 + n]);
    W2Tp[p] = f2bf(W2[((e << 9) + n) * 512 + k]);
}
__global__ void pack_W1(const float* __restrict__ W1, ushort_t* __restrict__ W1p) {
    int p = blockIdx.x * 256 + threadIdx.x;
    if (p >= EE * 4 * 32 * 512) return;
    int j = p & 7, L = (p >> 3) & 63, ct = (p >> 9) & 31, ks = (p >> 14) & 3, e = p >> 16;
    int k = ks * 32 + ((L >> 4) << 3) + j;
    int n = (ct << 4) + (L & 15);
    W1p[p] = (k < FPD) ? f2bf(W1[(e * FPD + k) * 512 + n]) : (ushort_t)0;
}
__global__ void pack_W1T(const float* __restrict__ W1, ushort_t* __restrict__ W1Tp) {
    int p = blockIdx.x * 256 + threadIdx.x;
    if (p >= EE * 16 * 8 * 512) return;
    int j = p & 7, L = (p >> 3) & 63, ct = (p >> 9) & 7, ks = (p >> 12) & 15, e = p >> 16;
    int k = ks * 32 + ((L >> 4) << 3) + j;
    int n = (ct << 4) + (L & 15);
    W1Tp[p] = (n < FPD) ? f2bf(W1[(e * FPD + n) * 512 + k]) : (ushort_t)0;
}

#define STR 520
#define FSTR 136

// ---------------- fused fwd+bwd MLP, 32 atoms/block, MFMA ----------------
__global__ __launch_bounds__(256) void mlp_mfma(
    const float* __restrict__ fps, const int* __restrict__ image_idx,
    const float* __restrict__ b1, const float* __restrict__ b2,
    const float* __restrict__ W3, const float* __restrict__ b3,
    const ushort_t* __restrict__ W1p, const ushort_t* __restrict__ W2p,
    const ushort_t* __restrict__ W2Tp, const ushort_t* __restrict__ W1Tp,
    const int* __restrict__ counts, const int* __restrict__ lists,
    float* __restrict__ energy, ushort_t* __restrict__ g) {
    __shared__ ushort_t sH1[32 * STR];
    __shared__ ushort_t sD[32 * STR];
    __shared__ float sW3[512];
    __shared__ float eAcc[32];
    __shared__ int sAtom[32];
    __shared__ int sImg[32];

    const int e = blockIdx.x % EE;
    const int tile = blockIdx.x / EE;
    const int cnt = counts[e];
    const int base = tile * 32;
    if (base >= cnt) return;
    const int nA = min(32, cnt - base);
    const int* lst = lists + e * N_ATOMS + base;

    const int t = threadIdx.x;
    const int w = t >> 6, lane = t & 63, quad = lane >> 4, lc = lane & 15;

    if (t < 32) {
        int a = (t < nA) ? lst[t] : -1;
        sAtom[t] = a;
        sImg[t] = (a >= 0) ? image_idx[a] : 0;
        eAcc[t] = 0.f;
    }
    for (int i = t; i < 512; i += 256) sW3[i] = W3[e * 512 + i];
    for (int i = t; i < 32 * 128; i += 256) {
        int a = i >> 7, f = i & 127;
        float v = 0.f;
        if (f < FPD && a < nA) v = fps[(long long)lst[a] * FPD + f];
        sD[a * FSTR + f] = f2bf(v);
    }
    __syncthreads();

    float b1c[8], b2c[8];
#pragma unroll
    for (int ct = 0; ct < 8; ct++) {
        int col = w * 128 + ct * 16 + lc;
        b1c[ct] = b1[e * 512 + col];
        b2c[ct] = b2[e * 512 + col];
    }

    f32x4 acc[2][8];

    // ---- stage 1: h1 = tanh(fp @ W1 + b1) ----
#pragma unroll
    for (int rt = 0; rt < 2; rt++)
#pragma unroll
        for (int ct = 0; ct < 8; ct++) acc[rt][ct] = (f32x4)0.f;
#pragma unroll
    for (int ks = 0; ks < 4; ks++) {
        bf16x8 a0 = *(const bf16x8*)((const char*)sD + lc * (FSTR * 2) + ks * 64 + quad * 16);
        bf16x8 a1 = *(const bf16x8*)((const char*)sD + (16 + lc) * (FSTR * 2) + ks * 64 + quad * 16);
#pragma unroll
        for (int ct = 0; ct < 8; ct++) {
            BF8 b;
            b.f = *(const f32x4*)(W1p + ((size_t)((e * 4 + ks) * 32 + w * 8 + ct) * 512) + lane * 8);
            acc[0][ct] = __builtin_amdgcn_mfma_f32_16x16x32_bf16(a0, b.h, acc[0][ct], 0, 0, 0);
            acc[1][ct] = __builtin_amdgcn_mfma_f32_16x16x32_bf16(a1, b.h, acc[1][ct], 0, 0, 0);
        }
    }
#pragma unroll
    for (int ct = 0; ct < 8; ct++) {
        int col = w * 128 + ct * 16 + lc;
#pragma unroll
        for (int rt = 0; rt < 2; rt++)
#pragma unroll
            for (int r = 0; r < 4; r++) {
                int row = rt * 16 + quad * 4 + r;
                sH1[row * STR + col] = f2bf(fast_tanh(acc[rt][ct][r] + b1c[ct]));
            }
    }
    __syncthreads();

    // ---- stage 2: h2 = tanh(h1 @ W2 + b2); dh2 = W3*(1-h2^2); energy ----
#pragma unroll
    for (int rt = 0; rt < 2; rt++)
#pragma unroll
        for (int ct = 0; ct < 8; ct++) acc[rt][ct] = (f32x4)0.f;
#pragma unroll 2
    for (int ks = 0; ks < 16; ks++) {
        bf16x8 a0 = *(const bf16x8*)((const char*)sH1 + lc * (STR * 2) + ks * 64 + quad * 16);
        bf16x8 a1 = *(const bf16x8*)((const char*)sH1 + (16 + lc) * (STR * 2) + ks * 64 + quad * 16);
#pragma unroll
        for (int ct = 0; ct < 8; ct++) {
            BF8 b;
            b.f = *(const f32x4*)(W2p + ((size_t)((e * 16 + ks) * 32 + w * 8 + ct) * 512) + lane * 8);
            acc[0][ct] = __builtin_amdgcn_mfma_f32_16x16x32_bf16(a0, b.h, acc[0][ct], 0, 0, 0);
            acc[1][ct] = __builtin_amdgcn_mfma_f32_16x16x32_bf16(a1, b.h, acc[1][ct], 0, 0, 0);
        }
    }
    {
        float ep[2][4];
#pragma unroll
        for (int rt = 0; rt < 2; rt++)
#pragma unroll
            for (int r = 0; r < 4; r++) ep[rt][r] = 0.f;
#pragma unroll
        for (int ct = 0; ct < 8; ct++) {
            int col = w * 128 + ct * 16 + lc;
            float w3c = sW3[col];
#pragma unroll
            for (int rt = 0; rt < 2; rt++)
#pragma unroll
                for (int r = 0; r < 4; r++) {
                    int row = rt * 16 + quad * 4 + r;
                    float h2 = fast_tanh(acc[rt][ct][r] + b2c[ct]);
                    ep[rt][r] += h2 * w3c;
                    sD[row * STR + col] = f2bf(w3c * (1.f - h2 * h2));
                }
        }
#pragma unroll
        for (int rt = 0; rt < 2; rt++)
#pragma unroll
            for (int r = 0; r < 4; r++) {
                float p = ep[rt][r];
                p += __shfl_xor(p, 1);
                p += __shfl_xor(p, 2);
                p += __shfl_xor(p, 4);
                p += __shfl_xor(p, 8);
                if (lc == 0) atomicAdd(&eAcc[rt * 16 + quad * 4 + r], p);
            }
    }
    __syncthreads();

    if (t < nA) atomicAdd(&energy[sImg[t]], eAcc[t] + b3[e]);

    // ---- stage 5: dh1 = (dh2 @ W2^T) * (1-h1^2) ----
#pragma unroll
    for (int rt = 0; rt < 2; rt++)
#pragma unroll
        for (int ct = 0; ct < 8; ct++) acc[rt][ct] = (f32x4)0.f;
#pragma unroll 2
    for (int ks = 0; ks < 16; ks++) {
        bf16x8 a0 = *(const bf16x8*)((const char*)sD + lc * (STR * 2) + ks * 64 + quad * 16);
        bf16x8 a1 = *(const bf16x8*)((const char*)sD + (16 + lc) * (STR * 2) + ks * 64 + quad * 16);
#pragma unroll
        for (int ct = 0; ct < 8; ct++) {
            BF8 b;
            b.f = *(const f32x4*)(W2Tp + ((size_t)((e * 16 + ks) * 32 + w * 8 + ct) * 512) + lane * 8);
            acc[0][ct] = __builtin_amdgcn_mfma_f32_16x16x32_bf16(a0, b.h, acc[0][ct], 0, 0, 0);
            acc[1][ct] = __builtin_amdgcn_mfma_f32_16x16x32_bf16(a1, b.h, acc[1][ct], 0, 0, 0);
        }
    }
#pragma unroll
    for (int ct = 0; ct < 8; ct++) {
        int col = w * 128 + ct * 16 + lc;
#pragma unroll
        for (int rt = 0; rt < 2; rt++)
#pragma unroll
            for (int r = 0; r < 4; r++) {
                int row = rt * 16 + quad * 4 + r;
                float h1v = bf2f(sH1[row * STR + col]);
                acc[rt][ct][r] *= (1.f - h1v * h1v);
            }
    }
    __syncthreads();
#pragma unroll
    for (int ct = 0; ct < 8; ct++) {
        int col = w * 128 + ct * 16 + lc;
#pragma unroll
        for (int rt = 0; rt < 2; rt++)
#pragma unroll
            for (int r = 0; r < 4; r++) {
                int row = rt * 16 + quad * 4 + r;
                sH1[row * STR + col] = f2bf(acc[rt][ct][r]);
            }
    }
    __syncthreads();

    // ---- stage 7: g = dh1 @ W1^T ----
    f32x4 acc7[2][2];
#pragma unroll
    for (int rt = 0; rt < 2; rt++)
#pragma unroll
        for (int c = 0; c < 2; c++) acc7[rt][c] = (f32x4)0.f;
#pragma unroll 2
    for (int ks = 0; ks < 16; ks++) {
        bf16x8 a0 = *(const bf16x8*)((const char*)sH1 + lc * (STR * 2) + ks * 64 + quad * 16);
        bf16x8 a1 = *(const bf16x8*)((const char*)sH1 + (16 + lc) * (STR * 2) + ks * 64 + quad * 16);
#pragma unroll
        for (int c = 0; c < 2; c++) {
            BF8 b;
            b.f = *(const f32x4*)(W1Tp + ((size_t)((e * 16 + ks) * 8 + w * 2 + c) * 512) + lane * 8);
            acc7[0][c] = __builtin_amdgcn_mfma_f32_16x16x32_bf16(a0, b.h, acc7[0][c], 0, 0, 0);
            acc7[1][c] = __builtin_amdgcn_mfma_f32_16x16x32_bf16(a1, b.h, acc7[1][c], 0, 0, 0);
        }
    }
#pragma unroll
    for (int c = 0; c < 2; c++) {
        int col = (w * 2 + c) * 16 + lc;
#pragma unroll
        for (int rt = 0; rt < 2; rt++)
#pragma unroll
            for (int r = 0; r < 4; r++) {
                int row = rt * 16 + quad * 4 + r;
                if (col < FPD && row < nA)
                    g[(long long)sAtom[row] * FPD + col] = f2bf(acc7[rt][c][r]);
            }
    }
}

// ---------------- sparse force scatter, XCD-privatized, 4 nnz/thread ---------
__global__ __launch_bounds__(256) void scatter_forces(
    const int* __restrict__ rows, const int* __restrict__ cols,
    const float* __restrict__ vals, const ushort_t* __restrict__ g,
    float* __restrict__ forcesP) {
    int k = blockIdx.x * 256 + threadIdx.x;
    if (k >= NNZ_C / 4) return;
    int slot = blockIdx.x & 7;  // ~XCD id under round-robin dispatch
    int4 r = ((const int4*)rows)[k];
    int4 c = ((const int4*)cols)[k];
    float4 v = ((const float4*)vals)[k];
    float* fp = forcesP + (size_t)slot * NFORCE;
    atomicAdd(&fp[c.x], -v.x * bf2f(g[r.x]));
    atomicAdd(&fp[c.y], -v.y * bf2f(g[r.y]));
    atomicAdd(&fp[c.z], -v.z * bf2f(g[r.z]));
    atomicAdd(&fp[c.w], -v.w * bf2f(g[r.w]));
}

__global__ void reduce_forces(const float* __restrict__ forcesP, float* __restrict__ forces) {
    int i = blockIdx.x * blockDim.x + threadIdx.x;
    if (i >= NFORCE) return;
    float s = 0.f;
#pragma unroll
    for (int x = 0; x < 8; x++) s += forcesP[x * NFORCE + i];
    forces[i] = s;
}

extern "C" void kernel_launch(void* const* d_in, const int* in_sizes, int n_in,
                              void* d_out, int out_size, void* d_ws, size_t ws_size,
                              hipStream_t stream) {
    const float* fps = (const float*)d_in[0];
    const int* z = (const int*)d_in[1];
    const int* img = (const int*)d_in[2];
    const float* W1 = (const float*)d_in[3];
    const float* b1 = (const float*)d_in[4];
    const float* W2 = (const float*)d_in[5];
    const float* b2 = (const float*)d_in[6];
    const float* W3 = (const float*)d_in[7];
    const float* b3 = (const float*)d_in[8];
    const int* rows = (const int*)d_in[9];
    const int* cols = (const int*)d_in[10];
    const float* vals = (const float*)d_in[11];

    float* out = (float*)d_out;
    float* energy = out;
    float* forces = out + BB;

    char* ws = (char*)d_ws;
    int* counts = (int*)ws;                           // 256 B
    int* lists = (int*)(ws + 256);                    // 720000 B
    ushort_t* W1p = (ushort_t*)(ws + 720384);         // 393216 B
    ushort_t* W2p = (ushort_t*)(ws + 1113600);        // 1572864 B
    ushort_t* W2Tp = (ushort_t*)(ws + 2686464);       // 1572864 B
    ushort_t* W1Tp = (ushort_t*)(ws + 4259328);       // 393216 B
    ushort_t* g = (ushort_t*)(ws + 4652544);          // 14400000 B
    float* forcesP = (float*)(ws + 19052544);         // 5760000 B -> 24812544
    (void)in_sizes; (void)n_in; (void)out_size; (void)ws_size;

    hipMemsetAsync(d_out, 0, (size_t)(BB + NFORCE) * sizeof(float), stream);
    hipMemsetAsync(counts, 0, 256, stream);
    hipMemsetAsync(forcesP, 0, (size_t)8 * NFORCE * sizeof(float), stream);

    build_lists<<<(N_ATOMS + 255) / 256, 256, 0, stream>>>(z, counts, lists);
    pack_W2<<<(EE * 16 * 32 * 512 + 255) / 256, 256, 0, stream>>>(W2, W2p, W2Tp);
    pack_W1<<<(EE * 4 * 32 * 512 + 255) / 256, 256, 0, stream>>>(W1, W1p);
    pack_W1T<<<(EE * 16 * 8 * 512 + 255) / 256, 256, 0, stream>>>(W1, W1Tp);

    int tiles = (N_ATOMS + 31) / 32;
    mlp_mfma<<<EE * tiles, 256, 0, stream>>>(fps, img, b1, b2, W3, b3,
                                             W1p, W2p, W2Tp, W1Tp,
                                             counts, lists, energy, g);
    scatter_forces<<<(NNZ_C / 4 + 255) / 256, 256, 0, stream>>>(rows, cols, vals, g, forcesP);
    reduce_forces<<<(NFORCE + 255) / 256, 256, 0, stream>>>(forcesP, forces);
}

// Round 5
// 636.385 us; speedup vs baseline: 4.1009x; 1.0549x over previous
//
#include <hip/hip_runtime.h>

#define N_ATOMS 60000
#define FPD 120
#define HD 512
#define EE 3
#define BB 600
#define NNZ_C 5000000
#define NFORCE (3 * N_ATOMS)

typedef unsigned short ushort_t;
typedef unsigned int uint_t;
typedef __attribute__((ext_vector_type(8))) __bf16 bf16x8;
typedef __attribute__((ext_vector_type(4))) float f32x4;

union BF8 { f32x4 f; bf16x8 h; };

__device__ __forceinline__ ushort_t f2bf(float x) {
    uint_t u = __builtin_bit_cast(uint_t, x);
    u = (u + 0x7FFFu + ((u >> 16) & 1u)) >> 16;
    return (ushort_t)u;
}
__device__ __forceinline__ float bf2f(ushort_t s) {
    uint_t u = ((uint_t)s) << 16;
    return __builtin_bit_cast(float, u);
}
__device__ __forceinline__ float fast_tanh(float x) {
    float e2 = __expf(2.f * x);
    return fmaf(-2.f, __frcp_rn(e2 + 1.f), 1.f);
}

// ---------------- build per-element atom lists (block-aggregated atomics) -----
__global__ __launch_bounds__(256) void build_lists(const int* __restrict__ z,
                                                   int* __restrict__ counts,
                                                   int* __restrict__ lists) {
    __shared__ int lc[3];
    __shared__ int lbase[3];
    const int t = threadIdx.x;
    if (t < 3) lc[t] = 0;
    __syncthreads();
    const int i = blockIdx.x * 256 + t;
    int e = 0, pos = 0;
    if (i < N_ATOMS) {
        int zi = z[i];
        e = (zi == 1) ? 0 : ((zi == 8) ? 1 : 2);
        pos = atomicAdd(&lc[e], 1);
    }
    __syncthreads();
    if (t < 3) lbase[t] = atomicAdd(&counts[t], lc[t]);
    __syncthreads();
    if (i < N_ATOMS) lists[e * N_ATOMS + lbase[e] + pos] = i;
}

// ---------------- pack weights into MFMA B-fragment order (bf16) ----------------
// Lane L of B-frag holds B[k = ks*32 + (L>>4)*8 + j][n = ct*16 + (L&15)], j=0..7.
// ks OUTER, ct inner -> per-iteration wave loads span 8KB contiguous.
__global__ void pack_W2(const float* __restrict__ W2, ushort_t* __restrict__ W2p,
                        ushort_t* __restrict__ W2Tp) {
    int p = blockIdx.x * 256 + threadIdx.x;
    if (p >= EE * 16 * 32 * 512) return;
    int j = p & 7, L = (p >> 3) & 63, ct = (p >> 9) & 31, ks = (p >> 14) & 15, e = p >> 18;
    int k = ks * 32 + ((L >> 4) << 3) + j;
    int n = (ct << 4) + (L & 15);
    W2p[p]  = f2bf(W2[((e << 9) + k) * 512 + n]);
    W2Tp[p] = f2bf(W2[((e << 9) + n) * 512 + k]);
}
__global__ void pack_W1(const float* __restrict__ W1, ushort_t* __restrict__ W1p) {
    int p = blockIdx.x * 256 + threadIdx.x;
    if (p >= EE * 4 * 32 * 512) return;
    int j = p & 7, L = (p >> 3) & 63, ct = (p >> 9) & 31, ks = (p >> 14) & 3, e = p >> 16;
    int k = ks * 32 + ((L >> 4) << 3) + j;
    int n = (ct << 4) + (L & 15);
    W1p[p] = (k < FPD) ? f2bf(W1[(e * FPD + k) * 512 + n]) : (ushort_t)0;
}
__global__ void pack_W1T(const float* __restrict__ W1, ushort_t* __restrict__ W1Tp) {
    int p = blockIdx.x * 256 + threadIdx.x;
    if (p >= EE * 16 * 8 * 512) return;
    int j = p & 7, L = (p >> 3) & 63, ct = (p >> 9) & 7, ks = (p >> 12) & 15, e = p >> 16;
    int k = ks * 32 + ((L >> 4) << 3) + j;
    int n = (ct << 4) + (L & 15);
    W1Tp[p] = (n < FPD) ? f2bf(W1[(e * FPD + n) * 512 + k]) : (ushort_t)0;
}

#define STR 520
#define FSTR 136

// ---------------- fused fwd+bwd MLP, 32 atoms/block, MFMA ----------------
// K-loops use explicit 3-deep register rotation (prefetch ks+2) to hide the
// ~200cyc L2 weight-load latency (unpipelined this loop is 10% MfmaUtil).
__global__ __launch_bounds__(256, 2) void mlp_mfma(
    const float* __restrict__ fps, const int* __restrict__ image_idx,
    const float* __restrict__ b1, const float* __restrict__ b2,
    const float* __restrict__ W3, const float* __restrict__ b3,
    const ushort_t* __restrict__ W1p, const ushort_t* __restrict__ W2p,
    const ushort_t* __restrict__ W2Tp, const ushort_t* __restrict__ W1Tp,
    const int* __restrict__ counts, const int* __restrict__ lists,
    float* __restrict__ energy, ushort_t* __restrict__ g) {
    __shared__ ushort_t sH1[32 * STR];
    __shared__ ushort_t sD[32 * STR];
    __shared__ float sW3[512];
    __shared__ float eAcc[32];
    __shared__ int sAtom[32];
    __shared__ int sImg[32];

    const int e = blockIdx.x % EE;
    const int tile = blockIdx.x / EE;
    const int cnt = counts[e];
    const int base = tile * 32;
    if (base >= cnt) return;
    const int nA = min(32, cnt - base);
    const int* lst = lists + e * N_ATOMS + base;

    const int t = threadIdx.x;
    const int w = t >> 6, lane = t & 63, quad = lane >> 4, lc = lane & 15;

    if (t < 32) {
        int a = (t < nA) ? lst[t] : -1;
        sAtom[t] = a;
        sImg[t] = (a >= 0) ? image_idx[a] : 0;
        eAcc[t] = 0.f;
    }
    for (int i = t; i < 512; i += 256) sW3[i] = W3[e * 512 + i];
    for (int i = t; i < 32 * 128; i += 256) {
        int a = i >> 7, f = i & 127;
        float v = 0.f;
        if (f < FPD && a < nA) v = fps[(long long)lst[a] * FPD + f];
        sD[a * FSTR + f] = f2bf(v);
    }
    __syncthreads();

    float b1c[8], b2c[8];
#pragma unroll
    for (int ct = 0; ct < 8; ct++) {
        int col = w * 128 + ct * 16 + lc;
        b1c[ct] = b1[e * 512 + col];
        b2c[ct] = b2[e * 512 + col];
    }

    f32x4 acc[2][8];

    // ---- stage 1: h1 = tanh(fp @ W1 + b1), K=4 iters (compiler hoists) ----
#pragma unroll
    for (int rt = 0; rt < 2; rt++)
#pragma unroll
        for (int ct = 0; ct < 8; ct++) acc[rt][ct] = (f32x4)0.f;
    {
        const ushort_t* wbase = W1p + ((size_t)(e * 4) * 32 + w * 8) * 512 + lane * 8;
#pragma unroll
        for (int ks = 0; ks < 4; ks++) {
            bf16x8 a0 = *(const bf16x8*)((const char*)sD + lc * (FSTR * 2) + ks * 64 + quad * 16);
            bf16x8 a1 = *(const bf16x8*)((const char*)sD + (16 + lc) * (FSTR * 2) + ks * 64 + quad * 16);
#pragma unroll
            for (int ct = 0; ct < 8; ct++) {
                BF8 b;
                b.f = *(const f32x4*)(wbase + ((size_t)ks * 32 + ct) * 512);
                acc[0][ct] = __builtin_amdgcn_mfma_f32_16x16x32_bf16(a0, b.h, acc[0][ct], 0, 0, 0);
                acc[1][ct] = __builtin_amdgcn_mfma_f32_16x16x32_bf16(a1, b.h, acc[1][ct], 0, 0, 0);
            }
        }
    }
#pragma unroll
    for (int ct = 0; ct < 8; ct++) {
        int col = w * 128 + ct * 16 + lc;
#pragma unroll
        for (int rt = 0; rt < 2; rt++)
#pragma unroll
            for (int r = 0; r < 4; r++) {
                int row = rt * 16 + quad * 4 + r;
                sH1[row * STR + col] = f2bf(fast_tanh(acc[rt][ct][r] + b1c[ct]));
            }
    }
    __syncthreads();

    // ---- stage 2: h2 = tanh(h1 @ W2 + b2); dh2; energy ----
#pragma unroll
    for (int rt = 0; rt < 2; rt++)
#pragma unroll
        for (int ct = 0; ct < 8; ct++) acc[rt][ct] = (f32x4)0.f;
    {
        const ushort_t* wbase = W2p + ((size_t)(e * 16) * 32 + w * 8) * 512 + lane * 8;
        BF8 bb[3][8];
#pragma unroll
        for (int ct = 0; ct < 8; ct++) {
            bb[0][ct].f = *(const f32x4*)(wbase + (size_t)ct * 512);
            bb[1][ct].f = *(const f32x4*)(wbase + (size_t)(32 * 512) + ct * 512);
        }
#pragma unroll
        for (int ks = 0; ks < 16; ks++) {
            if (ks + 2 < 16) {
#pragma unroll
                for (int ct = 0; ct < 8; ct++)
                    bb[(ks + 2) % 3][ct].f =
                        *(const f32x4*)(wbase + (size_t)(ks + 2) * 32 * 512 + (size_t)ct * 512);
            }
            bf16x8 a0 = *(const bf16x8*)((const char*)sH1 + lc * (STR * 2) + ks * 64 + quad * 16);
            bf16x8 a1 = *(const bf16x8*)((const char*)sH1 + (16 + lc) * (STR * 2) + ks * 64 + quad * 16);
#pragma unroll
            for (int ct = 0; ct < 8; ct++) {
                acc[0][ct] = __builtin_amdgcn_mfma_f32_16x16x32_bf16(a0, bb[ks % 3][ct].h, acc[0][ct], 0, 0, 0);
                acc[1][ct] = __builtin_amdgcn_mfma_f32_16x16x32_bf16(a1, bb[ks % 3][ct].h, acc[1][ct], 0, 0, 0);
            }
        }
    }
    {
        float ep[2][4];
#pragma unroll
        for (int rt = 0; rt < 2; rt++)
#pragma unroll
            for (int r = 0; r < 4; r++) ep[rt][r] = 0.f;
#pragma unroll
        for (int ct = 0; ct < 8; ct++) {
            int col = w * 128 + ct * 16 + lc;
            float w3c = sW3[col];
#pragma unroll
            for (int rt = 0; rt < 2; rt++)
#pragma unroll
                for (int r = 0; r < 4; r++) {
                    int row = rt * 16 + quad * 4 + r;
                    float h2 = fast_tanh(acc[rt][ct][r] + b2c[ct]);
                    ep[rt][r] += h2 * w3c;
                    sD[row * STR + col] = f2bf(w3c * (1.f - h2 * h2));
                }
        }
#pragma unroll
        for (int rt = 0; rt < 2; rt++)
#pragma unroll
            for (int r = 0; r < 4; r++) {
                float p = ep[rt][r];
                p += __shfl_xor(p, 1);
                p += __shfl_xor(p, 2);
                p += __shfl_xor(p, 4);
                p += __shfl_xor(p, 8);
                if (lc == 0) atomicAdd(&eAcc[rt * 16 + quad * 4 + r], p);
            }
    }
    __syncthreads();

    if (t < nA) atomicAdd(&energy[sImg[t]], eAcc[t] + b3[e]);

    // ---- stage 5: dh1 = (dh2 @ W2^T) * (1-h1^2) ----
#pragma unroll
    for (int rt = 0; rt < 2; rt++)
#pragma unroll
        for (int ct = 0; ct < 8; ct++) acc[rt][ct] = (f32x4)0.f;
    {
        const ushort_t* wbase = W2Tp + ((size_t)(e * 16) * 32 + w * 8) * 512 + lane * 8;
        BF8 bb[3][8];
#pragma unroll
        for (int ct = 0; ct < 8; ct++) {
            bb[0][ct].f = *(const f32x4*)(wbase + (size_t)ct * 512);
            bb[1][ct].f = *(const f32x4*)(wbase + (size_t)(32 * 512) + ct * 512);
        }
#pragma unroll
        for (int ks = 0; ks < 16; ks++) {
            if (ks + 2 < 16) {
#pragma unroll
                for (int ct = 0; ct < 8; ct++)
                    bb[(ks + 2) % 3][ct].f =
                        *(const f32x4*)(wbase + (size_t)(ks + 2) * 32 * 512 + (size_t)ct * 512);
            }
            bf16x8 a0 = *(const bf16x8*)((const char*)sD + lc * (STR * 2) + ks * 64 + quad * 16);
            bf16x8 a1 = *(const bf16x8*)((const char*)sD + (16 + lc) * (STR * 2) + ks * 64 + quad * 16);
#pragma unroll
            for (int ct = 0; ct < 8; ct++) {
                acc[0][ct] = __builtin_amdgcn_mfma_f32_16x16x32_bf16(a0, bb[ks % 3][ct].h, acc[0][ct], 0, 0, 0);
                acc[1][ct] = __builtin_amdgcn_mfma_f32_16x16x32_bf16(a1, bb[ks % 3][ct].h, acc[1][ct], 0, 0, 0);
            }
        }
    }
#pragma unroll
    for (int ct = 0; ct < 8; ct++) {
        int col = w * 128 + ct * 16 + lc;
#pragma unroll
        for (int rt = 0; rt < 2; rt++)
#pragma unroll
            for (int r = 0; r < 4; r++) {
                int row = rt * 16 + quad * 4 + r;
                float h1v = bf2f(sH1[row * STR + col]);
                acc[rt][ct][r] *= (1.f - h1v * h1v);
            }
    }
    __syncthreads();
#pragma unroll
    for (int ct = 0; ct < 8; ct++) {
        int col = w * 128 + ct * 16 + lc;
#pragma unroll
        for (int rt = 0; rt < 2; rt++)
#pragma unroll
            for (int r = 0; r < 4; r++) {
                int row = rt * 16 + quad * 4 + r;
                sH1[row * STR + col] = f2bf(acc[rt][ct][r]);
            }
    }
    __syncthreads();

    // ---- stage 7: g = dh1 @ W1^T ----
    f32x4 acc7[2][2];
#pragma unroll
    for (int rt = 0; rt < 2; rt++)
#pragma unroll
        for (int c = 0; c < 2; c++) acc7[rt][c] = (f32x4)0.f;
    {
        const ushort_t* wbase = W1Tp + ((size_t)(e * 16) * 8 + w * 2) * 512 + lane * 8;
        BF8 bb[3][2];
#pragma unroll
        for (int c = 0; c < 2; c++) {
            bb[0][c].f = *(const f32x4*)(wbase + (size_t)c * 512);
            bb[1][c].f = *(const f32x4*)(wbase + (size_t)(8 * 512) + c * 512);
        }
#pragma unroll
        for (int ks = 0; ks < 16; ks++) {
            if (ks + 2 < 16) {
#pragma unroll
                for (int c = 0; c < 2; c++)
                    bb[(ks + 2) % 3][c].f =
                        *(const f32x4*)(wbase + (size_t)(ks + 2) * 8 * 512 + (size_t)c * 512);
            }
            bf16x8 a0 = *(const bf16x8*)((const char*)sH1 + lc * (STR * 2) + ks * 64 + quad * 16);
            bf16x8 a1 = *(const bf16x8*)((const char*)sH1 + (16 + lc) * (STR * 2) + ks * 64 + quad * 16);
#pragma unroll
            for (int c = 0; c < 2; c++) {
                acc7[0][c] = __builtin_amdgcn_mfma_f32_16x16x32_bf16(a0, bb[ks % 3][c].h, acc7[0][c], 0, 0, 0);
                acc7[1][c] = __builtin_amdgcn_mfma_f32_16x16x32_bf16(a1, bb[ks % 3][c].h, acc7[1][c], 0, 0, 0);
            }
        }
    }
#pragma unroll
    for (int c = 0; c < 2; c++) {
        int col = (w * 2 + c) * 16 + lc;
#pragma unroll
        for (int rt = 0; rt < 2; rt++)
#pragma unroll
            for (int r = 0; r < 4; r++) {
                int row = rt * 16 + quad * 4 + r;
                if (col < FPD && row < nA)
                    g[(long long)sAtom[row] * FPD + col] = f2bf(acc7[rt][c][r]);
            }
    }
}

// ---------------- sparse force scatter, privatized, 4 nnz/thread ---------
__global__ __launch_bounds__(256) void scatter_forces(
    const int* __restrict__ rows, const int* __restrict__ cols,
    const float* __restrict__ vals, const ushort_t* __restrict__ g,
    float* __restrict__ forcesP) {
    int k = blockIdx.x * 256 + threadIdx.x;
    if (k >= NNZ_C / 4) return;
    int slot = blockIdx.x & 7;
    int4 r = ((const int4*)rows)[k];
    int4 c = ((const int4*)cols)[k];
    float4 v = ((const float4*)vals)[k];
    float* fp = forcesP + (size_t)slot * NFORCE;
    atomicAdd(&fp[c.x], -v.x * bf2f(g[r.x]));
    atomicAdd(&fp[c.y], -v.y * bf2f(g[r.y]));
    atomicAdd(&fp[c.z], -v.z * bf2f(g[r.z]));
    atomicAdd(&fp[c.w], -v.w * bf2f(g[r.w]));
}

__global__ void reduce_forces(const float* __restrict__ forcesP, float* __restrict__ forces) {
    int i = blockIdx.x * blockDim.x + threadIdx.x;
    if (i >= NFORCE) return;
    float s = 0.f;
#pragma unroll
    for (int x = 0; x < 8; x++) s += forcesP[x * NFORCE + i];
    forces[i] = s;
}

extern "C" void kernel_launch(void* const* d_in, const int* in_sizes, int n_in,
                              void* d_out, int out_size, void* d_ws, size_t ws_size,
                              hipStream_t stream) {
    const float* fps = (const float*)d_in[0];
    const int* z = (const int*)d_in[1];
    const int* img = (const int*)d_in[2];
    const float* W1 = (const float*)d_in[3];
    const float* b1 = (const float*)d_in[4];
    const float* W2 = (const float*)d_in[5];
    const float* b2 = (const float*)d_in[6];
    const float* W3 = (const float*)d_in[7];
    const float* b3 = (const float*)d_in[8];
    const int* rows = (const int*)d_in[9];
    const int* cols = (const int*)d_in[10];
    const float* vals = (const float*)d_in[11];

    float* out = (float*)d_out;
    float* energy = out;
    float* forces = out + BB;

    char* ws = (char*)d_ws;
    int* counts = (int*)ws;                           // 256 B
    int* lists = (int*)(ws + 256);                    // 720000 B
    ushort_t* W1p = (ushort_t*)(ws + 720384);         // 393216 B
    ushort_t* W2p = (ushort_t*)(ws + 1113600);        // 1572864 B
    ushort_t* W2Tp = (ushort_t*)(ws + 2686464);       // 1572864 B
    ushort_t* W1Tp = (ushort_t*)(ws + 4259328);       // 393216 B
    ushort_t* g = (ushort_t*)(ws + 4652544);          // 14400000 B
    float* forcesP = (float*)(ws + 19052544);         // 5760000 B
    (void)in_sizes; (void)n_in; (void)out_size; (void)ws_size;

    hipMemsetAsync(d_out, 0, (size_t)(BB + NFORCE) * sizeof(float), stream);
    hipMemsetAsync(counts, 0, 256, stream);
    hipMemsetAsync(forcesP, 0, (size_t)8 * NFORCE * sizeof(float), stream);

    build_lists<<<(N_ATOMS + 255) / 256, 256, 0, stream>>>(z, counts, lists);
    pack_W2<<<(EE * 16 * 32 * 512 + 255) / 256, 256, 0, stream>>>(W2, W2p, W2Tp);
    pack_W1<<<(EE * 4 * 32 * 512 + 255) / 256, 256, 0, stream>>>(W1, W1p);
    pack_W1T<<<(EE * 16 * 8 * 512 + 255) / 256, 256, 0, stream>>>(W1, W1Tp);

    int tiles = (N_ATOMS + 31) / 32;
    mlp_mfma<<<EE * tiles, 256, 0, stream>>>(fps, img, b1, b2, W3, b3,
                                             W1p, W2p, W2Tp, W1Tp,
                                             counts, lists, energy, g);
    scatter_forces<<<(NNZ_C / 4 + 255) / 256, 256, 0, stream>>>(rows, cols, vals, g, forcesP);
    reduce_forces<<<(NFORCE + 255) / 256, 256, 0, stream>>>(forcesP, forces);
}